// Round 3
// baseline (941.626 us; speedup 1.0000x reference)
//
#include <hip/hip_runtime.h>
#include <hip/hip_bf16.h>
#include <cstdint>

#define S_LEN 2048
#define NH 16
#define DH 64
#define HD 1024
#define MROWS 4096   // B*S
#define KEXP 3072    // expanded K (hi|lo|hi / hi|hi|lo)
#define WINDOW 256

typedef __attribute__((ext_vector_type(4))) float f32x4;
typedef __attribute__((ext_vector_type(8))) __bf16 bf16v8;

__device__ __forceinline__ unsigned short f2bf(float f) {
  unsigned u = __float_as_uint(f);
  u += 0x7fffu + ((u >> 16) & 1u);
  return (unsigned short)(u >> 16);
}
__device__ __forceinline__ float bf2f(unsigned short b) {
  return __uint_as_float(((unsigned)b) << 16);
}

// fp32 [rows][1024] -> bf16 bits [rows][3072]
// lo_seg==1: [hi | lo | hi]  (A operand / activations)
// lo_seg==2: [hi | hi | lo]  (B operand / weights)
__global__ __launch_bounds__(256) void k_expand(const float* __restrict__ in,
                                                unsigned short* __restrict__ out,
                                                int rows, int lo_seg) {
  int idx = blockIdx.x * 256 + threadIdx.x;
  if (idx >= rows * 256) return;
  int row = idx >> 8, c4 = (idx & 255) * 4;
  const float4 x = reinterpret_cast<const float4*>(in)[idx];
  float xs[4] = {x.x, x.y, x.z, x.w};
  unsigned short h[4], l[4];
#pragma unroll
  for (int j = 0; j < 4; ++j) {
    h[j] = f2bf(xs[j]);
    l[j] = f2bf(xs[j] - bf2f(h[j]));
  }
  const ushort4 hv = make_ushort4(h[0], h[1], h[2], h[3]);
  const ushort4 lv = make_ushort4(l[0], l[1], l[2], l[3]);
  unsigned short* rp = out + (size_t)row * KEXP;
  *reinterpret_cast<ushort4*>(rp + c4)        = hv;
  *reinterpret_cast<ushort4*>(rp + 1024 + c4) = (lo_seg == 1) ? lv : hv;
  *reinterpret_cast<ushort4*>(rp + 2048 + c4) = (lo_seg == 1) ? hv : lv;
}

__global__ __launch_bounds__(256) void k_bias(const float* __restrict__ bq,
                                              const float* __restrict__ bk,
                                              const float* __restrict__ bv,
                                              float* __restrict__ out) {
  int i = blockIdx.x * 256 + threadIdx.x;
  if (i >= 3072) return;
  out[i] = (i < 1024) ? bq[i] : (i < 2048 ? bk[i - 1024] : bv[i - 2048]);
}

#define GLOAD16(g, l)                                                           \
  __builtin_amdgcn_global_load_lds((const __attribute__((address_space(1))) void*)(g), \
                                   (__attribute__((address_space(3))) void*)(l), 16, 0, 0)

// C[m][n] = sum_k A[m][k]*B[n][k] + bias[n]; A:[M][K] bf16, B:[N][K] bf16, C fp32 [M][ldc]
__global__ __launch_bounds__(256) void k_gemm(const unsigned short* __restrict__ A,
                                              const unsigned short* __restrict__ B,
                                              float* __restrict__ C,
                                              const float* __restrict__ bias,
                                              int M, int N, int K, int ldc) {
  __shared__ unsigned short As[128 * 32];
  __shared__ unsigned short Bs[128 * 32];
  const int m0 = blockIdx.y * 128, n0 = blockIdx.x * 128;
  const int t = threadIdx.x;
  const int lane = t & 63, w = t >> 6;
  const int wm = w >> 1, wn = w & 1;
  f32x4 acc[4][4] = {};
  const unsigned short* Ag = A + (size_t)(m0 + w * 32 + (lane >> 2)) * K + (lane & 3) * 8;
  const unsigned short* Bg = B + (size_t)(n0 + w * 32 + (lane >> 2)) * K + (lane & 3) * 8;
  unsigned short* Asb = As + w * 32 * 32;
  unsigned short* Bsb = Bs + w * 32 * 32;
  const int fr = lane & 15, fk = (lane >> 4) * 8;

  for (int k0 = 0; k0 < K; k0 += 32) {
    GLOAD16(Ag + k0, Asb);
    GLOAD16(Ag + k0 + 16 * K, Asb + 16 * 32);
    GLOAD16(Bg + k0, Bsb);
    GLOAD16(Bg + k0 + 16 * K, Bsb + 16 * 32);
    __syncthreads();
    bf16v8 af[4], bfr[4];
#pragma unroll
    for (int m = 0; m < 4; ++m)
      af[m] = *reinterpret_cast<const bf16v8*>(&As[(wm * 64 + m * 16 + fr) * 32 + fk]);
#pragma unroll
    for (int n = 0; n < 4; ++n)
      bfr[n] = *reinterpret_cast<const bf16v8*>(&Bs[(wn * 64 + n * 16 + fr) * 32 + fk]);
#pragma unroll
    for (int m = 0; m < 4; ++m)
#pragma unroll
      for (int n = 0; n < 4; ++n)
        acc[m][n] = __builtin_amdgcn_mfma_f32_16x16x32_bf16(af[m], bfr[n], acc[m][n], 0, 0, 0);
    __syncthreads();
  }

  const int fg = lane >> 4;
#pragma unroll
  for (int n = 0; n < 4; ++n) {
    const int col = n0 + wn * 64 + n * 16 + fr;
    const float bb = bias ? bias[col] : 0.0f;
#pragma unroll
    for (int m = 0; m < 4; ++m) {
      const int row = m0 + wm * 64 + m * 16 + fg * 4;
#pragma unroll
      for (int r = 0; r < 4; ++r)
        C[(size_t)(row + r) * ldc + col] = acc[m][n][r] + bb;
    }
  }
}

// In-place RMSNorm of Q (cols 0..1023) and K (cols 1024..2047) segments of 64
__global__ __launch_bounds__(256) void k_rms(float* __restrict__ QKV,
                                             const float* __restrict__ qn,
                                             const float* __restrict__ kn) {
  const int t = threadIdx.x;
  const int wv = t >> 6, d = t & 63;
  const int blk = blockIdx.x;                 // 0 .. 4096*8-1
  const int row = blk >> 3;
  const int seg = (blk & 7) * 4 + wv;         // 0..31 -> cols seg*64
  float* p = QKV + (size_t)row * KEXP + seg * 64 + d;
  float x = *p;
  float ss = x * x;
#pragma unroll
  for (int off = 32; off; off >>= 1) ss += __shfl_xor(ss, off, 64);
  const float r = rsqrtf(ss * (1.0f / 64.0f) + 1e-6f);
  const float* wvec = (seg < 16) ? qn : kn;
  *p = x * r * wvec[d];
}

__global__ __launch_bounds__(256) void k_attn(const float* __restrict__ QKV,
                                              float* __restrict__ attn,
                                              float* __restrict__ ctx) {
  const int qt = blockIdx.x, h = blockIdx.y, b = blockIdx.z;
  const int i0 = qt * 64;
  const int t = threadIdx.x;
  const int tq = t >> 4, tk = t & 15;
  __shared__ float Qs[64][65];
  __shared__ float KVs[64][65];   // K in phase A, V in phase C
  __shared__ float Pt[64][65];    // P transposed [k][q]

  {  // stage Q tile
    const int r = t >> 2, c = (t & 3) * 16;
    const float* src = QKV + (size_t)(b * S_LEN + i0 + r) * KEXP + h * DH + c;
#pragma unroll
    for (int j = 0; j < 16; j += 4)
      *reinterpret_cast<float4*>(&Qs[r][c + j]) = *reinterpret_cast<const float4*>(src + j);
  }

  const int cs = (qt >= 4) ? (qt - 4) : 0;   // first key chunk (5 chunks always)
  float sreg[5][4][4];
  const float scale = 0.125f;

#pragma unroll
  for (int c = 0; c < 5; ++c) {
    const int k0 = (cs + c) * 64;
    __syncthreads();
    {  // stage K chunk
      const int r = t >> 2, cc = (t & 3) * 16;
      const float* src = QKV + (size_t)(b * S_LEN + k0 + r) * KEXP + HD + h * DH + cc;
#pragma unroll
      for (int j = 0; j < 16; j += 4)
        *reinterpret_cast<float4*>(&KVs[r][cc + j]) = *reinterpret_cast<const float4*>(src + j);
    }
    __syncthreads();
    float acc[4][4] = {};
#pragma unroll 4
    for (int d = 0; d < 64; d += 4) {
      float4 qv[4], kv[4];
#pragma unroll
      for (int q = 0; q < 4; ++q) qv[q] = *reinterpret_cast<const float4*>(&Qs[tq * 4 + q][d]);
#pragma unroll
      for (int k = 0; k < 4; ++k) kv[k] = *reinterpret_cast<const float4*>(&KVs[tk * 4 + k][d]);
#pragma unroll
      for (int q = 0; q < 4; ++q)
#pragma unroll
        for (int k = 0; k < 4; ++k)
          acc[q][k] += qv[q].x * kv[k].x + qv[q].y * kv[k].y + qv[q].z * kv[k].z + qv[q].w * kv[k].w;
    }
#pragma unroll
    for (int q = 0; q < 4; ++q) {
      const int i = i0 + tq * 4 + q;
#pragma unroll
      for (int k = 0; k < 4; ++k) {
        const int j = k0 + tk * 4 + k;
        const bool valid = (j <= i) && (i - j < WINDOW);
        sreg[c][q][k] = valid ? acc[q][k] * scale : -1e30f;
      }
    }
  }

  // softmax across the row (16 lanes of same tq hold the row's 80 cols)
#pragma unroll
  for (int q = 0; q < 4; ++q) {
    float m = -1e30f;
#pragma unroll
    for (int c = 0; c < 5; ++c)
#pragma unroll
      for (int k = 0; k < 4; ++k) m = fmaxf(m, sreg[c][q][k]);
#pragma unroll
    for (int off = 8; off; off >>= 1) m = fmaxf(m, __shfl_xor(m, off, 16));
    float l = 0.f;
#pragma unroll
    for (int c = 0; c < 5; ++c)
#pragma unroll
      for (int k = 0; k < 4; ++k) {
        const float e = __expf(sreg[c][q][k] - m);
        sreg[c][q][k] = e;
        l += e;
      }
#pragma unroll
    for (int off = 8; off; off >>= 1) l += __shfl_xor(l, off, 16);
    const float inv = 1.0f / l;
#pragma unroll
    for (int c = 0; c < 5; ++c)
#pragma unroll
      for (int k = 0; k < 4; ++k) sreg[c][q][k] *= inv;
  }

  {  // write attn rows: zero-fill outside [cs*64, cs*64+320), probs inside
    const size_t bh = ((size_t)(b * NH + h)) * S_LEN;
    const float4 z = make_float4(0.f, 0.f, 0.f, 0.f);
#pragma unroll
    for (int q = 0; q < 4; ++q) {
      const int i = i0 + tq * 4 + q;
      float* arow = attn + (bh + i) * (size_t)S_LEN;
      for (int j4 = tk; j4 < cs * 16; j4 += 16)
        *reinterpret_cast<float4*>(&arow[j4 * 4]) = z;
      for (int j4 = (cs + 5) * 16 + tk; j4 < S_LEN / 4; j4 += 16)
        *reinterpret_cast<float4*>(&arow[j4 * 4]) = z;
#pragma unroll
      for (int c = 0; c < 5; ++c)
        *reinterpret_cast<float4*>(&arow[(cs + c) * 64 + tk * 4]) =
            make_float4(sreg[c][q][0], sreg[c][q][1], sreg[c][q][2], sreg[c][q][3]);
    }
  }

  // PV: ctx[q][d] += P[q][k] * V[k][d]
  float cacc[4][4] = {};
#pragma unroll
  for (int c = 0; c < 5; ++c) {
    const int k0 = (cs + c) * 64;
    __syncthreads();
    {  // stage V chunk (reuse KVs)
      const int r = t >> 2, cc = (t & 3) * 16;
      const float* src = QKV + (size_t)(b * S_LEN + k0 + r) * KEXP + 2 * HD + h * DH + cc;
#pragma unroll
      for (int j = 0; j < 16; j += 4)
        *reinterpret_cast<float4*>(&KVs[r][cc + j]) = *reinterpret_cast<const float4*>(src + j);
    }
#pragma unroll
    for (int q = 0; q < 4; ++q)
#pragma unroll
      for (int k = 0; k < 4; ++k)
        Pt[tk * 4 + k][tq * 4 + q] = sreg[c][q][k];
    __syncthreads();
#pragma unroll 4
    for (int k = 0; k < 64; ++k) {
      const float4 pv = *reinterpret_cast<const float4*>(&Pt[k][tq * 4]);
      const float4 vv = *reinterpret_cast<const float4*>(&KVs[k][tk * 4]);
      const float pa[4] = {pv.x, pv.y, pv.z, pv.w};
      const float va[4] = {vv.x, vv.y, vv.z, vv.w};
#pragma unroll
      for (int q = 0; q < 4; ++q)
#pragma unroll
        for (int dd = 0; dd < 4; ++dd) cacc[q][dd] += pa[q] * va[dd];
    }
  }
#pragma unroll
  for (int q = 0; q < 4; ++q)
    *reinterpret_cast<float4*>(&ctx[(size_t)(b * S_LEN + i0 + tq * 4 + q) * HD + h * DH + tk * 4]) =
        make_float4(cacc[q][0], cacc[q][1], cacc[q][2], cacc[q][3]);
}

extern "C" void kernel_launch(void* const* d_in, const int* in_sizes, int n_in,
                              void* d_out, int out_size, void* d_ws, size_t ws_size,
                              hipStream_t stream) {
  (void)in_sizes; (void)n_in; (void)out_size; (void)ws_size;
  const float* X  = (const float*)d_in[0];
  const float* Wq = (const float*)d_in[2];
  const float* bq = (const float*)d_in[3];
  const float* Wk = (const float*)d_in[4];
  const float* bk = (const float*)d_in[5];
  const float* Wv = (const float*)d_in[6];
  const float* bv = (const float*)d_in[7];
  const float* Wo = (const float*)d_in[8];
  const float* bo = (const float*)d_in[9];
  const float* qn = (const float*)d_in[10];
  const float* kn = (const float*)d_in[11];

  float* out  = (float*)d_out;
  float* attn = out + (size_t)MROWS * HD;

  char* ws = (char*)d_ws;
  unsigned short* Xe   = (unsigned short*)(ws);                 // 4096x3072 bf16 (also reused as Ce)
  unsigned short* Wqkv = (unsigned short*)(ws + 25165824);      // 3072x3072 bf16
  unsigned short* Weo  = (unsigned short*)(ws + 44040192);      // 1024x3072 bf16
  float* biasqkv       = (float*)(ws + 50331648);               // 3072 f32
  float* QKVr          = (float*)(ws + 50343936);               // 4096x3072 f32
  float* ctx           = (float*)(ws + 100675584);              // 4096x1024 f32

  // A operands (activations): [hi|lo|hi]; B operands (weights): [hi|hi|lo]
  k_expand<<<4096, 256, 0, stream>>>(X, Xe, 4096, 1);
  k_expand<<<1024, 256, 0, stream>>>(Wq, Wqkv, 1024, 2);
  k_expand<<<1024, 256, 0, stream>>>(Wk, Wqkv + (size_t)1024 * KEXP, 1024, 2);
  k_expand<<<1024, 256, 0, stream>>>(Wv, Wqkv + (size_t)2048 * KEXP, 1024, 2);
  k_expand<<<1024, 256, 0, stream>>>(Wo, Weo, 1024, 2);
  k_bias<<<12, 256, 0, stream>>>(bq, bk, bv, biasqkv);

  k_gemm<<<dim3(24, 32), 256, 0, stream>>>(Xe, Wqkv, QKVr, biasqkv, MROWS, 3072, KEXP, 3072);
  k_rms<<<MROWS * 8, 256, 0, stream>>>(QKVr, qn, kn);
  k_attn<<<dim3(32, NH, 2), 256, 0, stream>>>(QKVr, attn, ctx);
  k_expand<<<4096, 256, 0, stream>>>(ctx, Xe, 4096, 1);   // Xe reused as Ce
  k_gemm<<<dim3(8, 32), 256, 0, stream>>>(Xe, Weo, out, bo, MROWS, HD, KEXP, HD);
}

// Round 5
// 928.116 us; speedup vs baseline: 1.0146x; 1.0146x over previous
//
#include <hip/hip_runtime.h>
#include <hip/hip_bf16.h>
#include <cstdint>

#define S_LEN 2048
#define NH 16
#define DH 64
#define HD 1024
#define MROWS 4096   // B*S
#define KEXP 3072    // expanded K (hi|lo|hi for A / hi|hi|lo for B)
#define WINDOW 256

typedef __attribute__((ext_vector_type(4))) float f32x4;
typedef __attribute__((ext_vector_type(8))) __bf16 bf16v8;
typedef __attribute__((ext_vector_type(8))) unsigned short u16x8;

__device__ __forceinline__ unsigned short f2bf(float f) {
  unsigned u = __float_as_uint(f);
  u += 0x7fffu + ((u >> 16) & 1u);
  return (unsigned short)(u >> 16);
}
__device__ __forceinline__ float bf2f(unsigned short b) {
  return __uint_as_float(((unsigned)b) << 16);
}

// fp32 [rows][1024] -> bf16 bits [rows][3072]
// lo_seg==1: [hi | lo | hi]  (A operand / activations)
// lo_seg==2: [hi | hi | lo]  (B operand / weights)
__global__ __launch_bounds__(256) void k_expand(const float* __restrict__ in,
                                                unsigned short* __restrict__ out,
                                                int rows, int lo_seg) {
  int idx = blockIdx.x * 256 + threadIdx.x;
  if (idx >= rows * 256) return;
  int row = idx >> 8, c4 = (idx & 255) * 4;
  const float4 x = reinterpret_cast<const float4*>(in)[idx];
  float xs[4] = {x.x, x.y, x.z, x.w};
  unsigned short h[4], l[4];
#pragma unroll
  for (int j = 0; j < 4; ++j) {
    h[j] = f2bf(xs[j]);
    l[j] = f2bf(xs[j] - bf2f(h[j]));
  }
  const ushort4 hv = make_ushort4(h[0], h[1], h[2], h[3]);
  const ushort4 lv = make_ushort4(l[0], l[1], l[2], l[3]);
  unsigned short* rp = out + (size_t)row * KEXP;
  *reinterpret_cast<ushort4*>(rp + c4)        = hv;
  *reinterpret_cast<ushort4*>(rp + 1024 + c4) = (lo_seg == 1) ? lv : hv;
  *reinterpret_cast<ushort4*>(rp + 2048 + c4) = (lo_seg == 1) ? hv : lv;
}

__global__ __launch_bounds__(256) void k_bias(const float* __restrict__ bq,
                                              const float* __restrict__ bk,
                                              const float* __restrict__ bv,
                                              float* __restrict__ out) {
  int i = blockIdx.x * 256 + threadIdx.x;
  if (i >= 3072) return;
  out[i] = (i < 1024) ? bq[i] : (i < 2048 ? bk[i - 1024] : bv[i - 2048]);
}

#define GLOAD16(g, l)                                                           \
  __builtin_amdgcn_global_load_lds((const __attribute__((address_space(1))) void*)(g), \
                                   (__attribute__((address_space(3))) void*)(l), 16, 0, 0)

// QKV GEMM: C = Xe(4096x3072) * Wqkv(3072x3072)^T(+bias), fused RMSNorm(Q,K) and
// bf16 hi/lo plane emission. Grid (24,32).
__global__ __launch_bounds__(256) void k_gemm_qkv(
    const unsigned short* __restrict__ A, const unsigned short* __restrict__ B,
    const float* __restrict__ bias, const float* __restrict__ qn,
    const float* __restrict__ kn,
    unsigned short* __restrict__ Qhi, unsigned short* __restrict__ Qlo,
    unsigned short* __restrict__ Khi, unsigned short* __restrict__ Klo,
    unsigned short* __restrict__ Vhi) {
  const int K = KEXP;
  __shared__ unsigned short As[128 * 32];
  __shared__ unsigned short Bs[128 * 32];
  int f = blockIdx.y * 24 + blockIdx.x;          // 768 blocks = 96 per XCD
  f = (f & 7) * 96 + (f >> 3);                   // XCD-contiguous swizzle (bijective)
  const int m0 = (f / 24) * 128, n0 = (f % 24) * 128;
  const int t = threadIdx.x;
  const int lane = t & 63, w = t >> 6;
  const int wm = w >> 1, wn = w & 1;
  f32x4 acc[4][4] = {};
  const unsigned short* Ag = A + (size_t)(m0 + w * 32 + (lane >> 2)) * K + (lane & 3) * 8;
  const unsigned short* Bg = B + (size_t)(n0 + w * 32 + (lane >> 2)) * K + (lane & 3) * 8;
  unsigned short* Asb = As + w * 32 * 32;
  unsigned short* Bsb = Bs + w * 32 * 32;
  const int fr = lane & 15, fk = (lane >> 4) * 8;

  for (int k0 = 0; k0 < K; k0 += 32) {
    GLOAD16(Ag + k0, Asb);
    GLOAD16(Ag + k0 + 16 * K, Asb + 16 * 32);
    GLOAD16(Bg + k0, Bsb);
    GLOAD16(Bg + k0 + 16 * K, Bsb + 16 * 32);
    __syncthreads();
    bf16v8 af[4], bfr[4];
#pragma unroll
    for (int m = 0; m < 4; ++m)
      af[m] = *reinterpret_cast<const bf16v8*>(&As[(wm * 64 + m * 16 + fr) * 32 + fk]);
#pragma unroll
    for (int n = 0; n < 4; ++n)
      bfr[n] = *reinterpret_cast<const bf16v8*>(&Bs[(wn * 64 + n * 16 + fr) * 32 + fk]);
#pragma unroll
    for (int m = 0; m < 4; ++m)
#pragma unroll
      for (int n = 0; n < 4; ++n)
        acc[m][n] = __builtin_amdgcn_mfma_f32_16x16x32_bf16(af[m], bfr[n], acc[m][n], 0, 0, 0);
    __syncthreads();
  }

  // Epilogue: bias + (RMSNorm for Q/K) + hi/lo bf16 plane stores.
  // This wave's 4 n-frags cover cols [head_base, head_base+64) == one head.
  const int fg = lane >> 4;
  const int head_base = n0 + wn * 64;
  const int seg = head_base >> 10;          // 0=Q, 1=K, 2=V
  const int cseg = head_base & 1023;        // col within its 1024-plane
  const float* wnv = (seg == 0) ? qn : kn;
  float wreg[4];
#pragma unroll
  for (int n = 0; n < 4; ++n) wreg[n] = (seg < 2) ? wnv[n * 16 + fr] : 1.0f;
  float breg[4];
#pragma unroll
  for (int n = 0; n < 4; ++n) breg[n] = bias[head_base + n * 16 + fr];

#pragma unroll
  for (int m = 0; m < 4; ++m) {
#pragma unroll
    for (int r = 0; r < 4; ++r) {
      const int row = m0 + wm * 64 + m * 16 + fg * 4 + r;
      float v[4];
#pragma unroll
      for (int n = 0; n < 4; ++n) v[n] = acc[m][n][r] + breg[n];
      if (seg < 2) {
        float ss = v[0] * v[0] + v[1] * v[1] + v[2] * v[2] + v[3] * v[3];
        ss += __shfl_xor(ss, 1, 16);
        ss += __shfl_xor(ss, 2, 16);
        ss += __shfl_xor(ss, 4, 16);
        ss += __shfl_xor(ss, 8, 16);
        const float rr = rsqrtf(ss * (1.0f / 64.0f) + 1e-6f);
#pragma unroll
        for (int n = 0; n < 4; ++n) v[n] *= rr * wreg[n];
      }
      const size_t base = (size_t)row * 1024 + cseg;
#pragma unroll
      for (int n = 0; n < 4; ++n) {
        const unsigned short hi = f2bf(v[n]);
        const size_t off = base + n * 16 + fr;
        if (seg == 0) { Qhi[off] = hi; Qlo[off] = f2bf(v[n] - bf2f(hi)); }
        else if (seg == 1) { Khi[off] = hi; Klo[off] = f2bf(v[n] - bf2f(hi)); }
        else { Vhi[off] = hi; }
      }
    }
  }
}

// O GEMM: out = ctx(bf16x3 planes) * Weo^T + bo. Grid (8,32).
__global__ __launch_bounds__(256) void k_gemm_out(
    const unsigned short* __restrict__ Chi, const unsigned short* __restrict__ Clo,
    const unsigned short* __restrict__ B, const float* __restrict__ bias,
    float* __restrict__ C) {
  const int K = KEXP;
  __shared__ unsigned short As[128 * 32];
  __shared__ unsigned short Bs[128 * 32];
  int f = blockIdx.y * 8 + blockIdx.x;           // 256 blocks = 32 per XCD
  f = (f & 7) * 32 + (f >> 3);
  const int m0 = (f / 8) * 128, n0 = (f % 8) * 128;
  const int t = threadIdx.x;
  const int lane = t & 63, w = t >> 6;
  const int wm = w >> 1, wn = w & 1;
  f32x4 acc[4][4] = {};
  const int arow = m0 + w * 32 + (lane >> 2);
  const int ac8 = (lane & 3) * 8;
  const unsigned short* Bg = B + (size_t)(n0 + w * 32 + (lane >> 2)) * K + ac8;
  unsigned short* Asb = As + w * 32 * 32;
  unsigned short* Bsb = Bs + w * 32 * 32;
  const int fr = lane & 15, fk = (lane >> 4) * 8;

  for (int k0 = 0; k0 < K; k0 += 32) {
    const unsigned short* Ap = ((k0 >> 10) == 1) ? Clo : Chi;   // [hi|lo|hi]
    const int kc = (k0 & 1023) + ac8;
    GLOAD16(Ap + (size_t)arow * 1024 + kc, Asb);
    GLOAD16(Ap + (size_t)(arow + 16) * 1024 + kc, Asb + 16 * 32);
    GLOAD16(Bg + k0, Bsb);
    GLOAD16(Bg + k0 + 16 * K, Bsb + 16 * 32);
    __syncthreads();
    bf16v8 af[4], bfr[4];
#pragma unroll
    for (int m = 0; m < 4; ++m)
      af[m] = *reinterpret_cast<const bf16v8*>(&As[(wm * 64 + m * 16 + fr) * 32 + fk]);
#pragma unroll
    for (int n = 0; n < 4; ++n)
      bfr[n] = *reinterpret_cast<const bf16v8*>(&Bs[(wn * 64 + n * 16 + fr) * 32 + fk]);
#pragma unroll
    for (int m = 0; m < 4; ++m)
#pragma unroll
      for (int n = 0; n < 4; ++n)
        acc[m][n] = __builtin_amdgcn_mfma_f32_16x16x32_bf16(af[m], bfr[n], acc[m][n], 0, 0, 0);
    __syncthreads();
  }

  const int fg = lane >> 4;
#pragma unroll
  for (int n = 0; n < 4; ++n) {
    const int col = n0 + wn * 64 + n * 16 + fr;
    const float bb = bias[col];
#pragma unroll
    for (int m = 0; m < 4; ++m) {
      const int row = m0 + wm * 64 + m * 16 + fg * 4;
#pragma unroll
      for (int r = 0; r < 4; ++r)
        C[(size_t)(row + r) * 1024 + col] = acc[m][n][r] + bb;
    }
  }
}

// MFMA attention. Grid (32, NH, 2), 256 threads (4 waves, wave w owns q-rows w*16..+15).
// QK^T swapped mfma(K,Q) in bf16x3; softmax in-register (lane = one q-row);
// PV via bf16x2 P x bf16 V through LDS.
__global__ __launch_bounds__(256) void k_attn(
    const unsigned short* __restrict__ Qhi, const unsigned short* __restrict__ Qlo,
    const unsigned short* __restrict__ Khi, const unsigned short* __restrict__ Klo,
    const unsigned short* __restrict__ Vhi,
    float* __restrict__ attn,
    unsigned short* __restrict__ Chi, unsigned short* __restrict__ Clo) {
  const int qt = blockIdx.x, h = blockIdx.y, b = blockIdx.z;
  const int i0 = qt * 64;
  const int t = threadIdx.x, lane = t & 63, w = t >> 6;
  const int fr = lane & 15, fg = lane >> 4, fk = fg * 8;
  const int cs = (qt >= 4) ? (qt - 4) : 0;   // 5 key chunks [cs*64, cs*64+320)

  __shared__ unsigned short Ph[4][16][72];
  __shared__ unsigned short Pl[4][16][72];
  __shared__ unsigned short Vt[64][72];      // V transposed [d][k]

  // Q fragments for this wave's q-rows (row = fr), d-windows 0 and 32.
  const size_t qoff = (size_t)(b * S_LEN + i0 + w * 16 + fr) * 1024 + h * DH;
  const bf16v8 qh0 = *reinterpret_cast<const bf16v8*>(Qhi + qoff + fk);
  const bf16v8 qh1 = *reinterpret_cast<const bf16v8*>(Qhi + qoff + 32 + fk);
  const bf16v8 ql0 = *reinterpret_cast<const bf16v8*>(Qlo + qoff + fk);
  const bf16v8 ql1 = *reinterpret_cast<const bf16v8*>(Qlo + qoff + 32 + fk);

  // QK^T: S^T[k][q] per chunk; lane holds q=fr, k = ff*16 + fg*4 + reg.
  f32x4 S[5][4] = {};
#pragma unroll
  for (int c = 0; c < 5; ++c) {
    const int k0 = (cs + c) * 64;
#pragma unroll
    for (int ff = 0; ff < 4; ++ff) {
      const size_t koff = (size_t)(b * S_LEN + k0 + ff * 16 + fr) * 1024 + h * DH;
      const bf16v8 kh0 = *reinterpret_cast<const bf16v8*>(Khi + koff + fk);
      const bf16v8 kh1 = *reinterpret_cast<const bf16v8*>(Khi + koff + 32 + fk);
      const bf16v8 kl0 = *reinterpret_cast<const bf16v8*>(Klo + koff + fk);
      const bf16v8 kl1 = *reinterpret_cast<const bf16v8*>(Klo + koff + 32 + fk);
      f32x4 a = S[c][ff];
      a = __builtin_amdgcn_mfma_f32_16x16x32_bf16(kh0, qh0, a, 0, 0, 0);
      a = __builtin_amdgcn_mfma_f32_16x16x32_bf16(kh1, qh1, a, 0, 0, 0);
      a = __builtin_amdgcn_mfma_f32_16x16x32_bf16(kl0, qh0, a, 0, 0, 0);
      a = __builtin_amdgcn_mfma_f32_16x16x32_bf16(kl1, qh1, a, 0, 0, 0);
      a = __builtin_amdgcn_mfma_f32_16x16x32_bf16(kh0, ql0, a, 0, 0, 0);
      a = __builtin_amdgcn_mfma_f32_16x16x32_bf16(kh1, ql1, a, 0, 0, 0);
      S[c][ff] = a;
    }
  }

  // Mask + softmax. Lane's q-row:
  const int qrow = i0 + w * 16 + fr;
  const float scale = 0.125f;
#pragma unroll
  for (int c = 0; c < 5; ++c)
#pragma unroll
    for (int ff = 0; ff < 4; ++ff)
#pragma unroll
      for (int r = 0; r < 4; ++r) {
        const int kk = (cs + c) * 64 + ff * 16 + fg * 4 + r;
        const bool valid = (kk <= qrow) && (qrow - kk < WINDOW);
        S[c][ff][r] = valid ? S[c][ff][r] * scale : -1e30f;
      }
  float mx = -1e30f;
#pragma unroll
  for (int c = 0; c < 5; ++c)
#pragma unroll
    for (int ff = 0; ff < 4; ++ff)
#pragma unroll
      for (int r = 0; r < 4; ++r) mx = fmaxf(mx, S[c][ff][r]);
  mx = fmaxf(mx, __shfl_xor(mx, 16, 64));
  mx = fmaxf(mx, __shfl_xor(mx, 32, 64));
  float lsum = 0.f;
#pragma unroll
  for (int c = 0; c < 5; ++c)
#pragma unroll
    for (int ff = 0; ff < 4; ++ff)
#pragma unroll
      for (int r = 0; r < 4; ++r) {
        const float e = __expf(S[c][ff][r] - mx);
        S[c][ff][r] = e;
        lsum += e;
      }
  lsum += __shfl_xor(lsum, 16, 64);
  lsum += __shfl_xor(lsum, 32, 64);
  const float inv = 1.0f / lsum;
#pragma unroll
  for (int c = 0; c < 5; ++c)
#pragma unroll
    for (int ff = 0; ff < 4; ++ff)
#pragma unroll
      for (int r = 0; r < 4; ++r) S[c][ff][r] *= inv;

  // Write attn row (zeros outside the 5-chunk band, probs inside).
  {
    float* arow = attn + (((size_t)(b * NH + h)) * S_LEN + qrow) * S_LEN;
    const float4 z = make_float4(0.f, 0.f, 0.f, 0.f);
    for (int j4 = fg; j4 < cs * 16; j4 += 4)
      *reinterpret_cast<float4*>(&arow[j4 * 4]) = z;
    for (int j4 = (cs + 5) * 16 + fg; j4 < S_LEN / 4; j4 += 4)
      *reinterpret_cast<float4*>(&arow[j4 * 4]) = z;
#pragma unroll
    for (int c = 0; c < 5; ++c)
#pragma unroll
      for (int ff = 0; ff < 4; ++ff)
        *reinterpret_cast<float4*>(&arow[(cs + c) * 64 + ff * 16 + fg * 4]) =
            make_float4(S[c][ff][0], S[c][ff][1], S[c][ff][2], S[c][ff][3]);
  }

  // PV: ctx[q][d] = sum_k P[q][k] V[k][d], bf16x2 P x bf16 V.
  f32x4 o[4] = {};
#pragma unroll
  for (int c = 0; c < 5; ++c) {
    const int k0 = (cs + c) * 64;
    __syncthreads();   // previous chunk's LDS fully consumed
    {  // stage V transposed: Vt[d][k]
      const int kk = t & 63, d0 = (t >> 6) * 16;
      const unsigned short* vp = Vhi + (size_t)(b * S_LEN + k0 + kk) * 1024 + h * DH + d0;
      const u16x8 a = *reinterpret_cast<const u16x8*>(vp);
      const u16x8 bvec = *reinterpret_cast<const u16x8*>(vp + 8);
#pragma unroll
      for (int j = 0; j < 8; ++j) {
        Vt[d0 + j][kk] = a[j];
        Vt[d0 + 8 + j][kk] = bvec[j];
      }
    }
    {  // write P hi/lo for this wave's q-rows: row q=fr, k = ff*16+fg*4+r
#pragma unroll
      for (int ff = 0; ff < 4; ++ff)
#pragma unroll
        for (int r = 0; r < 4; ++r) {
          const float p = S[c][ff][r];
          const unsigned short hi = f2bf(p);
          Ph[w][fr][ff * 16 + fg * 4 + r] = hi;
          Pl[w][fr][ff * 16 + fg * 4 + r] = f2bf(p - bf2f(hi));
        }
    }
    __syncthreads();
    const bf16v8 ph0 = *reinterpret_cast<const bf16v8*>(&Ph[w][fr][fk]);
    const bf16v8 ph1 = *reinterpret_cast<const bf16v8*>(&Ph[w][fr][32 + fk]);
    const bf16v8 pl0 = *reinterpret_cast<const bf16v8*>(&Pl[w][fr][fk]);
    const bf16v8 pl1 = *reinterpret_cast<const bf16v8*>(&Pl[w][fr][32 + fk]);
#pragma unroll
    for (int nf = 0; nf < 4; ++nf) {
      const bf16v8 v0 = *reinterpret_cast<const bf16v8*>(&Vt[nf * 16 + fr][fk]);
      const bf16v8 v1 = *reinterpret_cast<const bf16v8*>(&Vt[nf * 16 + fr][32 + fk]);
      f32x4 a = o[nf];
      a = __builtin_amdgcn_mfma_f32_16x16x32_bf16(ph0, v0, a, 0, 0, 0);
      a = __builtin_amdgcn_mfma_f32_16x16x32_bf16(ph1, v1, a, 0, 0, 0);
      a = __builtin_amdgcn_mfma_f32_16x16x32_bf16(pl0, v0, a, 0, 0, 0);
      a = __builtin_amdgcn_mfma_f32_16x16x32_bf16(pl1, v1, a, 0, 0, 0);
      o[nf] = a;
    }
  }

  // ctx write as bf16 hi/lo planes. Lane holds q = w*16 + fg*4 + r, d = nf*16 + fr.
#pragma unroll
  for (int nf = 0; nf < 4; ++nf)
#pragma unroll
    for (int r = 0; r < 4; ++r) {
      const int q2 = i0 + w * 16 + fg * 4 + r;
      const float val = o[nf][r];
      const unsigned short hi = f2bf(val);
      const size_t off = (size_t)(b * S_LEN + q2) * 1024 + h * DH + nf * 16 + fr;
      Chi[off] = hi;
      Clo[off] = f2bf(val - bf2f(hi));
    }
}

extern "C" void kernel_launch(void* const* d_in, const int* in_sizes, int n_in,
                              void* d_out, int out_size, void* d_ws, size_t ws_size,
                              hipStream_t stream) {
  (void)in_sizes; (void)n_in; (void)out_size; (void)ws_size;
  const float* X  = (const float*)d_in[0];
  const float* Wq = (const float*)d_in[2];
  const float* bq = (const float*)d_in[3];
  const float* Wk = (const float*)d_in[4];
  const float* bk = (const float*)d_in[5];
  const float* Wv = (const float*)d_in[6];
  const float* bv = (const float*)d_in[7];
  const float* Wo = (const float*)d_in[8];
  const float* bo = (const float*)d_in[9];
  const float* qn = (const float*)d_in[10];
  const float* kn = (const float*)d_in[11];

  float* out  = (float*)d_out;
  float* attn = out + (size_t)MROWS * HD;

  char* ws = (char*)d_ws;
  unsigned short* Xe   = (unsigned short*)(ws);                 // 4096x3072 bf16
  unsigned short* Wqkv = (unsigned short*)(ws + 25165824);      // 3072x3072 bf16
  unsigned short* Weo  = (unsigned short*)(ws + 44040192);      // 1024x3072 bf16
  float* biasqkv       = (float*)(ws + 50331648);               // 3072 f32
  unsigned short* Qhi  = (unsigned short*)(ws + 50343936);      // 4096x1024 bf16 planes
  unsigned short* Qlo  = (unsigned short*)(ws + 58732544);
  unsigned short* Khi  = (unsigned short*)(ws + 67121152);
  unsigned short* Klo  = (unsigned short*)(ws + 75509760);
  unsigned short* Vhi  = (unsigned short*)(ws + 83898368);
  unsigned short* Chi  = (unsigned short*)(ws + 92286976);
  unsigned short* Clo  = (unsigned short*)(ws + 100675584);     // ends 109,064,192

  k_expand<<<4096, 256, 0, stream>>>(X, Xe, 4096, 1);
  k_expand<<<1024, 256, 0, stream>>>(Wq, Wqkv, 1024, 2);
  k_expand<<<1024, 256, 0, stream>>>(Wk, Wqkv + (size_t)1024 * KEXP, 1024, 2);
  k_expand<<<1024, 256, 0, stream>>>(Wv, Wqkv + (size_t)2048 * KEXP, 1024, 2);
  k_expand<<<1024, 256, 0, stream>>>(Wo, Weo, 1024, 2);
  k_bias<<<12, 256, 0, stream>>>(bq, bk, bv, biasqkv);

  k_gemm_qkv<<<dim3(24, 32), 256, 0, stream>>>(Xe, Wqkv, biasqkv, qn, kn,
                                               Qhi, Qlo, Khi, Klo, Vhi);
  k_attn<<<dim3(32, NH, 2), 256, 0, stream>>>(Qhi, Qlo, Khi, Klo, Vhi, attn, Chi, Clo);
  k_gemm_out<<<dim3(8, 32), 256, 0, stream>>>(Chi, Clo, Weo, bo, out);
}